// Round 4
// baseline (642.524 us; speedup 1.0000x reference)
//
#include <hip/hip_runtime.h>
#include <math.h>

#define NTOK 16384
#define DIM  4096
#define NE   64
#define TOPK 8
#define MT   32            // tokens per block
#define BK   64            // k-tile
#define KT   (DIM / BK)    // 64
#define NSEL 11            // candidates kept per token
#define EPS  2e-4f         // ambiguity threshold (our max err ~1e-5)
#define LDA  72            // bf16 row pitch in shorts (144 B: 16B-aligned, 2-way banks max)
#define LDSC 33            // score row pitch (floats), 32 tokens + pad

typedef __attribute__((ext_vector_type(8))) short short8;   // 8 x bf16 frag
typedef __attribute__((ext_vector_type(4))) float f32x4;

__device__ __forceinline__ unsigned short f2bf(float f) {
    union { float f; unsigned u; } c; c.f = f;
    unsigned u = c.u + 0x7FFFu + ((c.u >> 16) & 1u);   // RNE
    return (unsigned short)(u >> 16);
}
__device__ __forceinline__ float bf2f(unsigned short h) {
    union { unsigned u; float f; } c; c.u = ((unsigned)h) << 16;
    return c.f;
}

#define CV1(H,L,I,V) { float _e=(V); unsigned short _h=f2bf(_e); H[I]=(short)_h; L[I]=(short)f2bf(_e-bf2f(_h)); }
#define CV8(H,L,A,Bq) CV1(H,L,0,(A).x) CV1(H,L,1,(A).y) CV1(H,L,2,(A).z) CV1(H,L,3,(A).w) \
                      CV1(H,L,4,(Bq).x) CV1(H,L,5,(Bq).y) CV1(H,L,6,(Bq).z) CV1(H,L,7,(Bq).w)

__global__ __launch_bounds__(256) void router_kernel(
    const float* __restrict__ X,   // [16384, 4096]
    const float* __restrict__ W,   // [64, 4096]
    const float* __restrict__ Bv,  // [64]
    float* __restrict__ outP,      // [16384, 8]
    float* __restrict__ outI)      // [16384, 8] indices as float
{
    // GEMM phase: Ah/Al [32][LDA], Wh/Wl [64][LDA] bf16. Epilogue overlays S[64][LDSC] f32.
    __shared__ __align__(16) unsigned short sm[(2 * MT + 2 * NE) * LDA];   // 27648 B
    unsigned short* Ah = sm;
    unsigned short* Al = sm + MT * LDA;
    unsigned short* Wh = sm + 2 * MT * LDA;
    unsigned short* Wl = sm + (2 * MT + NE) * LDA;
    float* S = (float*)sm;

    const int tid  = threadIdx.x;
    const int m0   = blockIdx.x * MT;
    const int wvid = tid >> 6;        // 0..3
    const int lane = tid & 63;
    const int l15  = lane & 15;
    const int quad = lane >> 4;
    const int mt   = wvid >> 1;       // token tile 0..1
    const int n0   = (wvid & 1) * 2;  // expert tile base 0 or 2

    // staging maps: A-tile 32x64 (8 floats/thread), W-tile 64x64 (16 floats/thread)
    const int arow = tid >> 3;        // 0..31
    const int acol = (tid & 7) * 8;   // 0..56
    const int wrow = tid >> 2;        // 0..63
    const int wcol = (tid & 3) * 16;  // 0,16,32,48

    const float* Xp = X + (size_t)(m0 + arow) * DIM + acol;
    const float* Wp = W + (size_t)wrow * DIM + wcol;

    // 2-deep register prefetch: tiles kt and kt+1 in flight at all times
    float4 xb[2][2], wb[2][4];
#pragma unroll
    for (int b = 0; b < 2; ++b) {
        const float* xq = Xp + b * BK;
        const float* wq = Wp + b * BK;
        xb[b][0] = *(const float4*)(xq);
        xb[b][1] = *(const float4*)(xq + 4);
#pragma unroll
        for (int j = 0; j < 4; ++j) wb[b][j] = *(const float4*)(wq + j * 4);
    }

    f32x4 acc[2];
    acc[0] = acc[1] = (f32x4){0.f, 0.f, 0.f, 0.f};

    for (int kt = 0; kt < KT; ++kt) {
        const int b = kt & 1;
        __syncthreads();   // prior tile's LDS reads done
        // convert fp32 -> (hi,lo) bf16 and stage
        short8 ah, al, wh0, wl0, wh1, wl1;
        CV8(ah,  al,  xb[b][0], xb[b][1])
        CV8(wh0, wl0, wb[b][0], wb[b][1])
        CV8(wh1, wl1, wb[b][2], wb[b][3])
        *(short8*)&Ah[arow * LDA + acol]     = ah;
        *(short8*)&Al[arow * LDA + acol]     = al;
        *(short8*)&Wh[wrow * LDA + wcol]     = wh0;
        *(short8*)&Wh[wrow * LDA + wcol + 8] = wh1;
        *(short8*)&Wl[wrow * LDA + wcol]     = wl0;
        *(short8*)&Wl[wrow * LDA + wcol + 8] = wl1;
        __syncthreads();

        // refill this buffer with tile kt+2 (consumed two iterations from now)
        if (kt + 2 < KT) {
            const float* xq = Xp + (kt + 2) * BK;
            const float* wq = Wp + (kt + 2) * BK;
            xb[b][0] = *(const float4*)(xq);
            xb[b][1] = *(const float4*)(xq + 4);
#pragma unroll
            for (int j = 0; j < 4; ++j) wb[b][j] = *(const float4*)(wq + j * 4);
        }

        // MFMA: wave w -> tokens [16*mt,16*mt+16) x experts [(n0)*16,(n0+2)*16)
        // 3 passes (hh, hl, lh): dropped ll (error ~2e-6 RMS, EPS covers it)
#pragma unroll
        for (int ks = 0; ks < 2; ++ks) {
            const int ko = ks * 32 + quad * 8;
            const int ar = (mt * 16 + l15) * LDA + ko;
            short8 a_h = *(const short8*)&Ah[ar];
            short8 a_l = *(const short8*)&Al[ar];
#pragma unroll
            for (int j = 0; j < 2; ++j) {
                const int br = ((n0 + j) * 16 + l15) * LDA + ko;
                short8 b_h = *(const short8*)&Wh[br];
                short8 b_l = *(const short8*)&Wl[br];
                acc[j] = __builtin_amdgcn_mfma_f32_16x16x32_bf16(a_h, b_h, acc[j], 0, 0, 0);
                acc[j] = __builtin_amdgcn_mfma_f32_16x16x32_bf16(a_h, b_l, acc[j], 0, 0, 0);
                acc[j] = __builtin_amdgcn_mfma_f32_16x16x32_bf16(a_l, b_h, acc[j], 0, 0, 0);
            }
        }
    }

    // ---- scores -> LDS overlay: S[e][tok], e-major so topk scan is conflict-free ----
    __syncthreads();
#pragma unroll
    for (int j = 0; j < 2; ++j) {
        const int e = (n0 + j) * 16 + l15;
        float bb = Bv[e];
#pragma unroll
        for (int r = 0; r < 4; ++r) {
            // C/D layout (m89): col(n)=lane&15, row(m)=quad*4+r
            const int m = mt * 16 + quad * 4 + r;
            S[e * LDSC + m] = acc[j][r] + bb;
        }
    }
    __syncthreads();
    if (wvid != 0) return;

    // ---- wave 0: lanes 0..31 = tokens. Scan 64 experts, keep top-11 ----
    float v[NSEL]; int id[NSEL];
#pragma unroll
    for (int j = 0; j < NSEL; ++j) { v[j] = -INFINITY; id[j] = 0; }
    for (int e = 0; e < NE; ++e) {
        float cv = S[e * LDSC + (lane & 31)];
        int ci = e;
#pragma unroll
        for (int j = 0; j < NSEL; ++j) {
            bool gt = cv > v[j];     // strict: equal incoming (higher e) stays below
            float tv = gt ? v[j] : cv;
            int   ti = gt ? id[j] : ci;
            v[j]  = gt ? cv : v[j];
            id[j] = gt ? ci : id[j];
            cv = tv; ci = ti;
        }
    }

    double vd[NSEL];
#pragma unroll
    for (int j = 0; j < NSEL; ++j) vd[j] = (double)v[j];

    // mark ambiguous adjacent ranks (NaN-safe: lanes>=32 have v=-inf -> diff=NaN -> false)
    int mk = 0;
#pragma unroll
    for (int i = 0; i < NSEL - 1; ++i)
        if (v[i] - v[i + 1] < EPS) mk |= (1 << i) | (1 << (i + 1));

    // rescue tokens where a rank 0..7 boundary is ambiguous: exact fp64 dot, wave-cooperative
    bool need = (lane < MT) && ((mk & 0xFF) != 0);
    unsigned long long bal = __ballot(need);
    while (bal) {
        int t = __ffsll(bal) - 1; bal &= bal - 1;
        int tmk = __shfl(mk, t);
        const float* Xr = X + (size_t)(m0 + t) * DIM;
#pragma unroll
        for (int r = 0; r < NSEL; ++r) {
            if ((tmk >> r) & 1) {
                int e = __shfl(id[r], t);
                const float* Wr = W + (size_t)e * DIM;
                double s = 0.0;
#pragma unroll 4
                for (int i = 0; i < 16; ++i) {
                    float4 xx = *(const float4*)(Xr + i * 256 + lane * 4);
                    float4 ww = *(const float4*)(Wr + i * 256 + lane * 4);
                    s = fma((double)xx.x, (double)ww.x, s);
                    s = fma((double)xx.y, (double)ww.y, s);
                    s = fma((double)xx.z, (double)ww.z, s);
                    s = fma((double)xx.w, (double)ww.w, s);
                }
#pragma unroll
                for (int off = 1; off < 64; off <<= 1) s += __shfl_xor(s, off);
                s += (double)Bv[e];
                if (lane == t) vd[r] = s;
            }
        }
    }

    // re-sort marked-adjacent runs by fp64 value (desc), tie -> lower index
#pragma unroll 1
    for (int pass = 0; pass < NSEL; ++pass) {
#pragma unroll
        for (int i = 0; i < NSEL - 1; ++i) {
            if (((mk >> i) & 1) && ((mk >> (i + 1)) & 1)) {
                if ((vd[i + 1] > vd[i]) || (vd[i + 1] == vd[i] && id[i + 1] < id[i])) {
                    double td = vd[i]; vd[i] = vd[i + 1]; vd[i + 1] = td;
                    int ti = id[i]; id[i] = id[i + 1]; id[i + 1] = ti;
                }
            }
        }
    }

    // ---- softmax over top-8 + store ----
    if (lane < MT) {
        float ex[TOPK]; float sum = 0.f;
        double mx = vd[0];
#pragma unroll
        for (int j = 0; j < TOPK; ++j) { ex[j] = expf((float)(vd[j] - mx)); sum += ex[j]; }
        float inv = 1.f / sum;

        const size_t o = (size_t)(m0 + lane) * TOPK;
        float4 p0 = { ex[0] * inv, ex[1] * inv, ex[2] * inv, ex[3] * inv };
        float4 p1 = { ex[4] * inv, ex[5] * inv, ex[6] * inv, ex[7] * inv };
        float4 i0 = { (float)id[0], (float)id[1], (float)id[2], (float)id[3] };
        float4 i1 = { (float)id[4], (float)id[5], (float)id[6], (float)id[7] };
        *(float4*)(outP + o)     = p0;
        *(float4*)(outP + o + 4) = p1;
        *(float4*)(outI + o)     = i0;
        *(float4*)(outI + o + 4) = i1;
    }
}

extern "C" void kernel_launch(void* const* d_in, const int* in_sizes, int n_in,
                              void* d_out, int out_size, void* d_ws, size_t ws_size,
                              hipStream_t stream) {
    const float* X  = (const float*)d_in[0];
    const float* W  = (const float*)d_in[1];
    const float* Bv = (const float*)d_in[2];
    float* outP = (float*)d_out;
    float* outI = (float*)d_out + (size_t)NTOK * TOPK;

    dim3 grid(NTOK / MT);   // 512 -> 2 blocks/CU
    dim3 block(256);
    router_kernel<<<grid, block, 0, stream>>>(X, W, Bv, outP, outI);
}

// Round 5
// 429.901 us; speedup vs baseline: 1.4946x; 1.4946x over previous
//
#include <hip/hip_runtime.h>
#include <math.h>

#define NTOK 16384
#define DIM  4096
#define NE   64
#define TOPK 8
#define MT   32            // tokens per block
#define BK   64            // k-tile
#define KT   (DIM / BK)    // 64
#define NSEL 11            // candidates kept per token
#define EPS  2e-4f         // ambiguity threshold (our max err ~1e-5)
#define LDA  72            // bf16 row pitch in shorts (144 B: 16B-aligned, 2-way banks max)
#define LDSC 33            // score row pitch (floats), 32 tokens + pad

typedef __attribute__((ext_vector_type(8))) short short8;   // 8 x bf16 frag
typedef __attribute__((ext_vector_type(4))) float f32x4;

__device__ __forceinline__ unsigned short f2bf(float f) {
    union { float f; unsigned u; } c; c.f = f;
    unsigned u = c.u + 0x7FFFu + ((c.u >> 16) & 1u);   // RNE
    return (unsigned short)(u >> 16);
}
__device__ __forceinline__ float bf2f(unsigned short h) {
    union { unsigned u; float f; } c; c.u = ((unsigned)h) << 16;
    return c.f;
}

#define CV1(H,L,I,V) { float _e=(V); unsigned short _h=f2bf(_e); H[I]=(short)_h; L[I]=(short)f2bf(_e-bf2f(_h)); }
#define CV8(H,L,A,Bq) CV1(H,L,0,(A).x) CV1(H,L,1,(A).y) CV1(H,L,2,(A).z) CV1(H,L,3,(A).w) \
                      CV1(H,L,4,(Bq).x) CV1(H,L,5,(Bq).y) CV1(H,L,6,(Bq).z) CV1(H,L,7,(Bq).w)

__global__ __launch_bounds__(256, 2) void router_kernel(
    const float* __restrict__ X,   // [16384, 4096]
    const float* __restrict__ W,   // [64, 4096]
    const float* __restrict__ Bv,  // [64]
    float* __restrict__ outP,      // [16384, 8]
    float* __restrict__ outI)      // [16384, 8] indices as float
{
    // GEMM phase: Ah/Al [32][LDA], Wh/Wl [64][LDA] bf16. Epilogue overlays S[64][LDSC] f32.
    __shared__ __align__(16) unsigned short sm[(2 * MT + 2 * NE) * LDA];   // 27648 B
    unsigned short* Ah = sm;
    unsigned short* Al = sm + MT * LDA;
    unsigned short* Wh = sm + 2 * MT * LDA;
    unsigned short* Wl = sm + (2 * MT + NE) * LDA;
    float* S = (float*)sm;

    const int tid  = threadIdx.x;
    const int m0   = blockIdx.x * MT;
    const int wvid = tid >> 6;        // 0..3
    const int lane = tid & 63;
    const int l15  = lane & 15;
    const int quad = lane >> 4;
    const int mt   = wvid >> 1;       // token tile 0..1
    const int n0   = (wvid & 1) * 2;  // expert tile base 0 or 2

    // staging maps: A-tile 32x64 (8 floats/thread), W-tile 64x64 (16 floats/thread)
    const int arow = tid >> 3;        // 0..31
    const int acol = (tid & 7) * 8;   // 0..56
    const int wrow = tid >> 2;        // 0..63
    const int wcol = (tid & 3) * 16;  // 0,16,32,48

    const float* Xp = X + (size_t)(m0 + arow) * DIM + acol;
    const float* Wp = W + (size_t)wrow * DIM + wcol;

    f32x4 acc[2];
    acc[0] = acc[1] = (f32x4){0.f, 0.f, 0.f, 0.f};

    // 2-deep register prefetch, STATIC buffer names (runtime-indexed arrays spill to scratch!)
    float4 xb0[2], wb0[4], xb1[2], wb1[4];

    auto refill = [&](float4 (&xb)[2], float4 (&wb)[4], int ktn) __attribute__((always_inline)) {
        if (ktn < KT) {
            const float* xq = Xp + ktn * BK;
            const float* wq = Wp + ktn * BK;
            xb[0] = *(const float4*)(xq);
            xb[1] = *(const float4*)(xq + 4);
#pragma unroll
            for (int j = 0; j < 4; ++j) wb[j] = *(const float4*)(wq + j * 4);
        }
    };

    auto stage = [&](const float4 (&xb)[2], const float4 (&wb)[4]) __attribute__((always_inline)) {
        short8 ah, al, wh0, wl0, wh1, wl1;
        CV8(ah,  al,  xb[0], xb[1])
        CV8(wh0, wl0, wb[0], wb[1])
        CV8(wh1, wl1, wb[2], wb[3])
        *(short8*)&Ah[arow * LDA + acol]     = ah;
        *(short8*)&Al[arow * LDA + acol]     = al;
        *(short8*)&Wh[wrow * LDA + wcol]     = wh0;
        *(short8*)&Wh[wrow * LDA + wcol + 8] = wh1;
        *(short8*)&Wl[wrow * LDA + wcol]     = wl0;
        *(short8*)&Wl[wrow * LDA + wcol + 8] = wl1;
    };

    auto mfma_tile = [&]() __attribute__((always_inline)) {
        // wave w -> tokens [16*mt,16*mt+16) x experts [n0*16,(n0+2)*16)
        // 3 passes (hh, hl, lh): ll dropped (error ~2e-6 RMS, EPS covers it)
#pragma unroll
        for (int ks = 0; ks < 2; ++ks) {
            const int ko = ks * 32 + quad * 8;
            const int ar = (mt * 16 + l15) * LDA + ko;
            short8 a_h = *(const short8*)&Ah[ar];
            short8 a_l = *(const short8*)&Al[ar];
#pragma unroll
            for (int j = 0; j < 2; ++j) {
                const int br = ((n0 + j) * 16 + l15) * LDA + ko;
                short8 b_h = *(const short8*)&Wh[br];
                short8 b_l = *(const short8*)&Wl[br];
                acc[j] = __builtin_amdgcn_mfma_f32_16x16x32_bf16(a_h, b_h, acc[j], 0, 0, 0);
                acc[j] = __builtin_amdgcn_mfma_f32_16x16x32_bf16(a_h, b_l, acc[j], 0, 0, 0);
                acc[j] = __builtin_amdgcn_mfma_f32_16x16x32_bf16(a_l, b_h, acc[j], 0, 0, 0);
            }
        }
    };

    refill(xb0, wb0, 0);
    refill(xb1, wb1, 1);

    for (int ktp = 0; ktp < KT; ktp += 2) {
        __syncthreads();
        stage(xb0, wb0);
        __syncthreads();
        refill(xb0, wb0, ktp + 2);
        mfma_tile();

        __syncthreads();
        stage(xb1, wb1);
        __syncthreads();
        refill(xb1, wb1, ktp + 3);
        mfma_tile();
    }

    // ---- scores -> LDS overlay: S[e][tok], e-major so topk scan is conflict-free ----
    __syncthreads();
#pragma unroll
    for (int j = 0; j < 2; ++j) {
        const int e = (n0 + j) * 16 + l15;
        float bb = Bv[e];
#pragma unroll
        for (int r = 0; r < 4; ++r) {
            // C/D layout (m89): col(n)=lane&15, row(m)=quad*4+r
            const int m = mt * 16 + quad * 4 + r;
            S[e * LDSC + m] = acc[j][r] + bb;
        }
    }
    __syncthreads();
    if (wvid != 0) return;

    // ---- wave 0: lanes 0..31 = tokens. Scan 64 experts, keep top-11 ----
    float v[NSEL]; int id[NSEL];
#pragma unroll
    for (int j = 0; j < NSEL; ++j) { v[j] = -INFINITY; id[j] = 0; }
    for (int e = 0; e < NE; ++e) {
        float cv = S[e * LDSC + (lane & 31)];
        int ci = e;
#pragma unroll
        for (int j = 0; j < NSEL; ++j) {
            bool gt = cv > v[j];     // strict: equal incoming (higher e) stays below
            float tv = gt ? v[j] : cv;
            int   ti = gt ? id[j] : ci;
            v[j]  = gt ? cv : v[j];
            id[j] = gt ? ci : id[j];
            cv = tv; ci = ti;
        }
    }

    double vd[NSEL];
#pragma unroll
    for (int j = 0; j < NSEL; ++j) vd[j] = (double)v[j];

    // mark ambiguous adjacent ranks (NaN-safe: lanes>=32 have v=-inf -> diff=NaN -> false)
    int mk = 0;
#pragma unroll
    for (int i = 0; i < NSEL - 1; ++i)
        if (v[i] - v[i + 1] < EPS) mk |= (1 << i) | (1 << (i + 1));

    // rescue tokens where a rank 0..7 boundary is ambiguous: exact fp64 dot, wave-cooperative
    bool need = (lane < MT) && ((mk & 0xFF) != 0);
    unsigned long long bal = __ballot(need);
    while (bal) {
        int t = __ffsll(bal) - 1; bal &= bal - 1;
        int tmk = __shfl(mk, t);
        const float* Xr = X + (size_t)(m0 + t) * DIM;
#pragma unroll
        for (int r = 0; r < NSEL; ++r) {
            if ((tmk >> r) & 1) {
                int e = __shfl(id[r], t);
                const float* Wr = W + (size_t)e * DIM;
                double s = 0.0;
#pragma unroll 4
                for (int i = 0; i < 16; ++i) {
                    float4 xx = *(const float4*)(Xr + i * 256 + lane * 4);
                    float4 ww = *(const float4*)(Wr + i * 256 + lane * 4);
                    s = fma((double)xx.x, (double)ww.x, s);
                    s = fma((double)xx.y, (double)ww.y, s);
                    s = fma((double)xx.z, (double)ww.z, s);
                    s = fma((double)xx.w, (double)ww.w, s);
                }
#pragma unroll
                for (int off = 1; off < 64; off <<= 1) s += __shfl_xor(s, off);
                s += (double)Bv[e];
                if (lane == t) vd[r] = s;
            }
        }
    }

    // re-sort marked-adjacent runs by fp64 value (desc), tie -> lower index
#pragma unroll 1
    for (int pass = 0; pass < NSEL; ++pass) {
#pragma unroll
        for (int i = 0; i < NSEL - 1; ++i) {
            if (((mk >> i) & 1) && ((mk >> (i + 1)) & 1)) {
                if ((vd[i + 1] > vd[i]) || (vd[i + 1] == vd[i] && id[i + 1] < id[i])) {
                    double td = vd[i]; vd[i] = vd[i + 1]; vd[i + 1] = td;
                    int ti = id[i]; id[i] = id[i + 1]; id[i + 1] = ti;
                }
            }
        }
    }

    // ---- softmax over top-8 + store ----
    if (lane < MT) {
        float ex[TOPK]; float sum = 0.f;
        double mx = vd[0];
#pragma unroll
        for (int j = 0; j < TOPK; ++j) { ex[j] = expf((float)(vd[j] - mx)); sum += ex[j]; }
        float inv = 1.f / sum;

        const size_t o = (size_t)(m0 + lane) * TOPK;
        float4 p0 = { ex[0] * inv, ex[1] * inv, ex[2] * inv, ex[3] * inv };
        float4 p1 = { ex[4] * inv, ex[5] * inv, ex[6] * inv, ex[7] * inv };
        float4 i0 = { (float)id[0], (float)id[1], (float)id[2], (float)id[3] };
        float4 i1 = { (float)id[4], (float)id[5], (float)id[6], (float)id[7] };
        *(float4*)(outP + o)     = p0;
        *(float4*)(outP + o + 4) = p1;
        *(float4*)(outI + o)     = i0;
        *(float4*)(outI + o + 4) = i1;
    }
}

extern "C" void kernel_launch(void* const* d_in, const int* in_sizes, int n_in,
                              void* d_out, int out_size, void* d_ws, size_t ws_size,
                              hipStream_t stream) {
    const float* X  = (const float*)d_in[0];
    const float* W  = (const float*)d_in[1];
    const float* Bv = (const float*)d_in[2];
    float* outP = (float*)d_out;
    float* outI = (float*)d_out + (size_t)NTOK * TOPK;

    dim3 grid(NTOK / MT);   // 512 -> 2 blocks/CU
    dim3 block(256);
    router_kernel<<<grid, block, 0, stream>>>(X, W, Bv, outP, outI);
}